// Round 4
// baseline (2632.192 us; speedup 1.0000x reference)
//
#include <hip/hip_runtime.h>
#include <hip/hip_bf16.h>
#include <math.h>

// Problem constants
#define BB 64
#define TT 256
#define EE 300
#define DD 600
#define KP 608        // K padded to 19*32 for MFMA
#define HH 512
#define G4 2048
#define LL 9
#define NT (BB*TT)

typedef __attribute__((ext_vector_type(8))) short short8;   // 8 bf16
typedef __attribute__((ext_vector_type(4))) float floatx4;  // MFMA acc

// ---------------- Workspace layout (bytes) ----------------
#define XZF_OFF  ((size_t)0)
#define XZ_BYTES ((size_t)NT * G4 * 2)                  // 67108864
#define XZB_OFF  (XZF_OFF + XZ_BYTES)
#define HSR_OFF  (XZB_OFF + XZ_BYTES)                   // hs region, 33554432
#define HS_BYTES ((size_t)NT * HH * 2)                  // 16777216
#define HSF_OFF  (HSR_OFF)
#define HSB_OFF  (HSR_OFF + HS_BYTES)
// aliases inside hs region (dead before their overwriters run):
#define XG_OFF   (HSR_OFF)                              // 16384*608*2 (dead before lstm)
#define WKT_OFF  (HSR_OFF + 19922944)                   // 2*2048*608*2 (dead before lstm)
#define BP_OFF   (HSR_OFF + 25165824)                   // written after logits reads hs
#define WRT_OFF  (HSR_OFF + (size_t)2 * HS_BYTES)       // 2*2048*512*2 = 4194304
#define HB_OFF   (WRT_OFF + 4194304)                    // tagged u32: 2dir*2slot*64*512*4
#define HB_BYTES ((size_t)2 * 2 * BB * HH * 4)          // 524288
#define LEN_OFF  (HB_OFF + HB_BYTES)

// Output layout (floats)
#define OUT_LOGITS 0
#define OUT_LENS   (BB*TT*LL)
#define OUT_LL     (OUT_LENS + BB)
#define OUT_TAGS   (OUT_LL + BB)

// ---------------------------------------------------------------------------
// Prep 1: gather embeddings -> xg[n][608] bf16 (zero-padded K)
// ---------------------------------------------------------------------------
__global__ __launch_bounds__(256) void prep_xg(
    const int* __restrict__ text, const int* __restrict__ sent,
    const float* __restrict__ wemb, const float* __restrict__ semb,
    __hip_bfloat16* __restrict__ xg)
{
    int n = blockIdx.x;
    int ti = text[n], si = sent[n];
    __hip_bfloat16* o = xg + (size_t)n * KP;
    for (int k = threadIdx.x; k < KP; k += 256) {
        float v = 0.f;
        if (k < EE)      v = wemb[(size_t)ti * EE + k];
        else if (k < DD) v = semb[(size_t)si * EE + (k - EE)];
        o[k] = __float2bfloat16(v);
    }
}

// ---------------------------------------------------------------------------
// Prep 2: WkT[dir][n][k] bf16 (transposed, zero-padded to 608)
// ---------------------------------------------------------------------------
__global__ __launch_bounds__(256) void prep_wkT(
    const float* __restrict__ Wk_f, const float* __restrict__ Wk_b,
    __hip_bfloat16* __restrict__ WkT)
{
    int n = blockIdx.x, dir = blockIdx.y;
    const float* Wk = dir ? Wk_b : Wk_f;
    __hip_bfloat16* o = WkT + (size_t)dir * G4 * KP + (size_t)n * KP;
    for (int k = threadIdx.x; k < KP; k += 256)
        o[k] = __float2bfloat16(k < DD ? Wk[(size_t)k * G4 + n] : 0.f);
}

// ---------------------------------------------------------------------------
// Prep 3: WrT[dir][n][k] bf16 (transposed, K=512 exact)
// ---------------------------------------------------------------------------
__global__ __launch_bounds__(256) void prep_wrT(
    const float* __restrict__ Wr_f, const float* __restrict__ Wr_b,
    __hip_bfloat16* __restrict__ WrT)
{
    int n = blockIdx.x, dir = blockIdx.y;
    const float* Wr = dir ? Wr_b : Wr_f;
    __hip_bfloat16* o = WrT + (size_t)dir * G4 * HH + (size_t)n * HH;
    for (int k = threadIdx.x; k < HH; k += 256)
        o[k] = __float2bfloat16(Wr[(size_t)k * G4 + n]);
}

// ---------------------------------------------------------------------------
// Embed GEMM: xz[dir][n][col] = xg @ Wk + b   (bf16 MFMA, frags from L2)
// ---------------------------------------------------------------------------
__global__ __launch_bounds__(256) void embed_gemm(
    const __hip_bfloat16* __restrict__ xg,
    const __hip_bfloat16* __restrict__ WkT,
    const float* __restrict__ b_f, const float* __restrict__ b_b,
    __hip_bfloat16* __restrict__ xz_f, __hip_bfloat16* __restrict__ xz_b)
{
    int dir = blockIdx.z;
    const __hip_bfloat16* wt = WkT + (size_t)dir * G4 * KP;
    const float* bias = dir ? b_b : b_f;
    __hip_bfloat16* xz = dir ? xz_b : xz_f;

    int n0 = blockIdx.x * 64;
    int c0 = blockIdx.y * 64;
    int wave = threadIdx.x >> 6, lane = threadIdx.x & 63;
    int mt2 = (wave & 1) * 2;
    int nt2 = (wave >> 1) * 2;
    int lm = lane & 15, lk8 = (lane >> 4) * 8;

    const short8* ap[2], *bp[2];
    ap[0] = (const short8*)(xg + (size_t)(n0 + (mt2+0)*16 + lm) * KP + lk8);
    ap[1] = (const short8*)(xg + (size_t)(n0 + (mt2+1)*16 + lm) * KP + lk8);
    bp[0] = (const short8*)(wt + (size_t)(c0 + (nt2+0)*16 + lm) * KP + lk8);
    bp[1] = (const short8*)(wt + (size_t)(c0 + (nt2+1)*16 + lm) * KP + lk8);

    floatx4 acc[2][2] = {};
    for (int kc = 0; kc < KP/32; ++kc) {
        short8 a0 = ap[0][kc*4];
        short8 a1 = ap[1][kc*4];
        short8 b0 = bp[0][kc*4];
        short8 b1 = bp[1][kc*4];
        acc[0][0] = __builtin_amdgcn_mfma_f32_16x16x32_bf16(a0, b0, acc[0][0], 0,0,0);
        acc[0][1] = __builtin_amdgcn_mfma_f32_16x16x32_bf16(a0, b1, acc[0][1], 0,0,0);
        acc[1][0] = __builtin_amdgcn_mfma_f32_16x16x32_bf16(a1, b0, acc[1][0], 0,0,0);
        acc[1][1] = __builtin_amdgcn_mfma_f32_16x16x32_bf16(a1, b1, acc[1][1], 0,0,0);
    }

    float bias0 = bias[c0 + (nt2+0)*16 + lm];
    float bias1 = bias[c0 + (nt2+1)*16 + lm];
    int lr = (lane >> 4) * 4;
    #pragma unroll
    for (int mi = 0; mi < 2; ++mi)
        #pragma unroll
        for (int ni = 0; ni < 2; ++ni) {
            int col = c0 + (nt2+ni)*16 + lm;
            float bs = ni ? bias1 : bias0;
            #pragma unroll
            for (int r = 0; r < 4; ++r) {
                int row = n0 + (mt2+mi)*16 + lr + r;
                xz[(size_t)row * G4 + col] = __float2bfloat16(acc[mi][ni][r] + bs);
            }
        }
}

// ---------------------------------------------------------------------------
// Persistent LSTM. 256 blocks (1/CU) x 256 threads, cooperative.
// block = (dir, rowgroup16, hgroup16), wave = gate. Wr slice in regs.
// Cross-block h exchange via TAGGED u32 elements ((t+1)<<16 | bf16):
// consumers poll the data directly — tag travels atomically with the value,
// so detection and load are the same L3 round trip (no flags, no fences).
// WAR-safe: producer publishes tag t+1 only after consuming all tag-t data,
// which proves every peer has finished reading slot[(t+1)&1] (step t-1).
// ---------------------------------------------------------------------------
__global__ __launch_bounds__(256, 1) void lstm_coop(
    const __hip_bfloat16* __restrict__ xz_f, const __hip_bfloat16* __restrict__ xz_b,
    const __hip_bfloat16* __restrict__ WrT,   // [2][2048][512]
    unsigned* __restrict__ hbx,               // [2dir][2slot][64][512] tagged u32
    __hip_bfloat16* __restrict__ hs_f, __hip_bfloat16* __restrict__ hs_b)
{
    int blk = blockIdx.x;
    int dir = blk >> 7, sub = blk & 127;
    int r0 = (sub >> 5) * 16;     // 4 rowgroups
    int h0 = (sub & 31) * 16;     // 32 hgroups
    int tid = threadIdx.x;
    int gate = tid >> 6, lane = tid & 63;
    int lm = lane & 15, lk8 = (lane >> 4) * 8;

    const __hip_bfloat16* xz = dir ? xz_b : xz_f;
    __hip_bfloat16* hs = dir ? hs_b : hs_f;
    const __hip_bfloat16* wrt = WrT + (size_t)dir * G4 * HH;
    unsigned* hbd = hbx + (size_t)dir * 2 * BB * HH;

    // persistent weight fragments (gate's 16 cols x full K=512)
    short8 bfrag[16];
    {
        const short8* wp = (const short8*)(wrt + (size_t)(gate*HH + h0 + lm) * HH + lk8);
        #pragma unroll
        for (int kc = 0; kc < 16; ++kc) bfrag[kc] = wp[kc*4];
    }

    __shared__ unsigned short htile[16][520];   // h(t) rows r0..r0+15, padded
    __shared__ float zbuf[4][16][17];

    // epilogue mapping: threads 0..127 each own (row er, cols ec, ec+1)
    int er = tid >> 3, ec = (tid & 7) * 2;
    float c0st = 0.f, c1st = 0.f;

    // xz source rows for z-phase (wave handles rows (lane>>4)*4 + r)
    int zr = (lane >> 4) * 4;

    for (int t = 0; t < TT; ++t) {
        int tok = dir ? (TT - 1 - t) : t;

        // prefetch xz operand (independent of h) — hides L2 latency under poll
        float xzv[4];
        #pragma unroll
        for (int r = 0; r < 4; ++r) {
            int n = (r0 + zr + r) * TT + tok;
            xzv[r] = __bfloat162float(xz[(size_t)n * G4 + gate*HH + h0 + lm]);
        }

        // poll tagged h(t) tile: 32 coalesced u32 loads per thread
        {
            const unsigned* src = hbd + (size_t)(t & 1) * BB * HH + (size_t)r0 * HH;
            unsigned want = (unsigned)t;
            unsigned v[32];
            #pragma unroll
            for (int i = 0; i < 32; ++i)
                v[i] = __hip_atomic_load(src + tid + 256*i,
                        __ATOMIC_RELAXED, __HIP_MEMORY_SCOPE_AGENT);
            unsigned pend = 0;
            #pragma unroll
            for (int i = 0; i < 32; ++i)
                if ((v[i] >> 16) != want) pend |= (1u << i);
            while (pend) {
                #pragma unroll
                for (int i = 0; i < 32; ++i)
                    if (pend & (1u << i)) {
                        unsigned x = __hip_atomic_load(src + tid + 256*i,
                                __ATOMIC_RELAXED, __HIP_MEMORY_SCOPE_AGENT);
                        if ((x >> 16) == want) { v[i] = x; pend &= ~(1u << i); }
                    }
            }
            // stage into LDS (strip tags). e = tid + 256*i -> row e>>9, col e&511
            #pragma unroll
            for (int i = 0; i < 32; ++i) {
                int e = tid + 256*i;
                htile[e >> 9][e & 511] = (unsigned short)(v[i] & 0xffffu);
            }
        }
        __syncthreads();

        floatx4 acc = {};
        #pragma unroll
        for (int kc = 0; kc < 16; ++kc) {
            short8 a = *(const short8*)&htile[lm][kc * 32 + lk8];
            acc = __builtin_amdgcn_mfma_f32_16x16x32_bf16(a, bfrag[kc], acc, 0,0,0);
        }

        // publish z-tile to LDS for gate exchange
        #pragma unroll
        for (int r = 0; r < 4; ++r)
            zbuf[gate][zr + r][lm] = acc[r] + xzv[r];
        __syncthreads();

        if (tid < 128) {
            float zi0 = zbuf[0][er][ec],   zi1 = zbuf[0][er][ec+1];
            float zf0 = zbuf[1][er][ec],   zf1 = zbuf[1][er][ec+1];
            float zg0 = zbuf[2][er][ec],   zg1 = zbuf[2][er][ec+1];
            float zo0 = zbuf[3][er][ec],   zo1 = zbuf[3][er][ec+1];
            float si0 = 1.f/(1.f+__expf(-zi0)), si1 = 1.f/(1.f+__expf(-zi1));
            float sf0 = 1.f/(1.f+__expf(-zf0)), sf1 = 1.f/(1.f+__expf(-zf1));
            float so0 = 1.f/(1.f+__expf(-zo0)), so1 = 1.f/(1.f+__expf(-zo1));
            c0st = sf0 * c0st + si0 * tanhf(zg0);
            c1st = sf1 * c1st + si1 * tanhf(zg1);
            float h0v = so0 * tanhf(c0st);
            float h1v = so1 * tanhf(c1st);
            unsigned u0 = (unsigned)__builtin_bit_cast(unsigned short, __float2bfloat16(h0v));
            unsigned u1 = (unsigned)__builtin_bit_cast(unsigned short, __float2bfloat16(h1v));
            unsigned tag = (unsigned)(t + 1) << 16;
            unsigned long long payload =
                ((unsigned long long)(tag | u1) << 32) | (unsigned long long)(tag | u0);
            // tagged agent-scope store: tag+data atomic per u32 half
            __hip_atomic_store(
                (unsigned long long*)(hbd + (size_t)((t+1) & 1) * BB * HH
                                          + (size_t)(r0 + er) * HH + h0 + ec),
                payload, __ATOMIC_RELAXED, __HIP_MEMORY_SCOPE_AGENT);
            // plain row-major copy for downstream logits kernel
            *(unsigned*)(hs + ((size_t)(r0 + er) * TT + tok) * HH + h0 + ec) =
                u0 | (u1 << 16);
        }
        // no barrier needed here: next iteration's first __syncthreads
        // separates epilogue zbuf reads from the next zbuf writes.
    }
}

// ---------------------------------------------------------------------------
// logits = [hf, hb] @ Wd + bd
// ---------------------------------------------------------------------------
__global__ __launch_bounds__(64) void logits_kernel(
    const __hip_bfloat16* __restrict__ hs_f, const __hip_bfloat16* __restrict__ hs_b,
    const float* __restrict__ Wd, const float* __restrict__ bd,
    float* __restrict__ out)
{
    int n = blockIdx.x;
    int tid = threadIdx.x;
    __shared__ float red[64][10];
    float acc[LL] = {};
    for (int kk = 0; kk < 16; ++kk) {
        int k = kk * 64 + tid;
        float hv = (k < HH) ? __bfloat162float(hs_f[(size_t)n * HH + k])
                            : __bfloat162float(hs_b[(size_t)n * HH + (k - HH)]);
        const float* w = Wd + (size_t)k * LL;
        #pragma unroll
        for (int l = 0; l < LL; ++l) acc[l] += hv * w[l];
    }
    #pragma unroll
    for (int l = 0; l < LL; ++l) red[tid][l] = acc[l];
    __syncthreads();
    for (int s = 32; s > 0; s >>= 1) {
        if (tid < s)
            for (int l = 0; l < LL; ++l) red[tid][l] += red[tid + s][l];
        __syncthreads();
    }
    if (tid < LL) out[(size_t)n * LL + tid] = red[0][tid] + bd[tid];
}

// ---------------------------------------------------------------------------
// text lengths
// ---------------------------------------------------------------------------
__global__ __launch_bounds__(256) void lens_kernel(
    const int* __restrict__ text, float* __restrict__ out_lens, int* __restrict__ len_i)
{
    int b = blockIdx.x, tid = threadIdx.x;
    __shared__ int sred[256];
    sred[tid] = (text[b * TT + tid] != 0) ? 1 : 0;
    __syncthreads();
    for (int s = 128; s > 0; s >>= 1) {
        if (tid < s) sred[tid] += sred[tid + s];
        __syncthreads();
    }
    if (tid == 0) { out_lens[b] = (float)sred[0]; len_i[b] = sred[0]; }
}

// ---------------------------------------------------------------------------
// CRF log-likelihood + Viterbi decode (one block per batch item)
// ---------------------------------------------------------------------------
__global__ __launch_bounds__(128) void crf_kernel(
    const float* __restrict__ logits, const int* __restrict__ labels,
    const float* __restrict__ trans, const int* __restrict__ len_i,
    int* __restrict__ bp, float* __restrict__ out_ll, float* __restrict__ out_tags)
{
    int b = blockIdx.x, tid = threadIdx.x;
    int len = len_i[b];
    const float* lg = logits + (size_t)b * TT * LL;
    const int* lab = labels + b * TT;

    __shared__ float tr[81];
    __shared__ float alpha[LL], vit[LL], newa[LL], newv[LL];
    __shared__ int newbp[LL];
    __shared__ float partial[128];

    if (tid < 81) tr[tid] = trans[tid];
    if (tid < LL) { alpha[tid] = lg[tid]; vit[tid] = lg[tid]; }
    __syncthreads();

    float up = 0.f;
    for (int t = tid; t < TT; t += 128) {
        float m = (t < len) ? 1.f : 0.f;
        up += m * lg[t * LL + lab[t]];
        if (t >= 1) up += m * tr[lab[t - 1] * LL + lab[t]];
    }
    partial[tid] = up;
    __syncthreads();
    for (int s = 64; s > 0; s >>= 1) {
        if (tid < s) partial[tid] += partial[tid + s];
        __syncthreads();
    }

    for (int t = 1; t < TT; ++t) {
        bool m = t < len;
        if (tid < LL) {
            int j = tid;
            float mx = -1e30f;
            #pragma unroll
            for (int i = 0; i < LL; ++i) mx = fmaxf(mx, alpha[i] + tr[i * LL + j]);
            float s = 0.f;
            #pragma unroll
            for (int i = 0; i < LL; ++i) s += __expf(alpha[i] + tr[i * LL + j] - mx);
            newa[j] = mx + __logf(s) + lg[t * LL + j];
        } else if (tid >= 64 && tid < 64 + LL) {
            int j = tid - 64;
            float best = -1e30f; int bi = 0;
            #pragma unroll
            for (int i = 0; i < LL; ++i) {
                float sc = vit[i] + tr[i * LL + j];
                if (sc > best) { best = sc; bi = i; }
            }
            newv[j] = best + lg[t * LL + j];
            newbp[j] = bi;
        }
        __syncthreads();
        if (tid < LL) {
            if (m) alpha[tid] = newa[tid];
        } else if (tid >= 64 && tid < 64 + LL) {
            int j = tid - 64;
            if (m) vit[j] = newv[j];
            bp[((size_t)b * (TT - 1) + (t - 1)) * LL + j] = m ? newbp[j] : j;
        }
        __syncthreads();
    }

    if (tid == 0) {
        float mx = -1e30f;
        #pragma unroll
        for (int j = 0; j < LL; ++j) mx = fmaxf(mx, alpha[j]);
        float s = 0.f;
        #pragma unroll
        for (int j = 0; j < LL; ++j) s += __expf(alpha[j] - mx);
        out_ll[b] = partial[0] - (mx + __logf(s));

        float bv = vit[0]; int last = 0;
        #pragma unroll
        for (int j = 1; j < LL; ++j) if (vit[j] > bv) { bv = vit[j]; last = j; }
        out_tags[b * TT + (TT - 1)] = (float)last;
        int tag = last;
        for (int s2 = TT - 2; s2 >= 0; --s2) {
            tag = bp[((size_t)b * (TT - 1) + s2) * LL + tag];
            out_tags[b * TT + s2] = (float)tag;
        }
    }
}

// ---------------------------------------------------------------------------
extern "C" void kernel_launch(void* const* d_in, const int* in_sizes, int n_in,
                              void* d_out, int out_size, void* d_ws, size_t ws_size,
                              hipStream_t stream)
{
    const int*   text  = (const int*)d_in[0];
    const int*   sent  = (const int*)d_in[1];
    const int*   labels= (const int*)d_in[2];
    const float* wemb  = (const float*)d_in[3];
    const float* semb  = (const float*)d_in[4];
    const float* Wk_f  = (const float*)d_in[5];
    const float* Wr_f  = (const float*)d_in[6];
    const float* b_f   = (const float*)d_in[7];
    const float* Wk_b  = (const float*)d_in[8];
    const float* Wr_b  = (const float*)d_in[9];
    const float* b_b   = (const float*)d_in[10];
    const float* Wd    = (const float*)d_in[11];
    const float* bd    = (const float*)d_in[12];
    const float* trans = (const float*)d_in[13];
    float* out = (float*)d_out;

    char* ws = (char*)d_ws;
    __hip_bfloat16* xz_f = (__hip_bfloat16*)(ws + XZF_OFF);
    __hip_bfloat16* xz_b = (__hip_bfloat16*)(ws + XZB_OFF);
    __hip_bfloat16* hs_f = (__hip_bfloat16*)(ws + HSF_OFF);
    __hip_bfloat16* hs_b = (__hip_bfloat16*)(ws + HSB_OFF);
    __hip_bfloat16* xg   = (__hip_bfloat16*)(ws + XG_OFF);
    __hip_bfloat16* WkT  = (__hip_bfloat16*)(ws + WKT_OFF);
    __hip_bfloat16* WrT  = (__hip_bfloat16*)(ws + WRT_OFF);
    unsigned*       hbx  = (unsigned*)(ws + HB_OFF);
    int*      bp    = (int*)(ws + BP_OFF);
    int*      leni  = (int*)(ws + LEN_OFF);

    prep_xg <<<NT,  256, 0, stream>>>(text, sent, wemb, semb, xg);
    prep_wkT<<<dim3(G4, 2), 256, 0, stream>>>(Wk_f, Wk_b, WkT);
    prep_wrT<<<dim3(G4, 2), 256, 0, stream>>>(Wr_f, Wr_b, WrT);
    // zero tagged h exchange (tag 0 == h(0) = 0) + len scratch
    hipMemsetAsync(ws + HB_OFF, 0, HB_BYTES + 256, stream);

    embed_gemm<<<dim3(NT/64, G4/64, 2), 256, 0, stream>>>(
        xg, WkT, b_f, b_b, xz_f, xz_b);

    {
        void* args[] = { (void*)&xz_f, (void*)&xz_b, (void*)&WrT,
                         (void*)&hbx, (void*)&hs_f, (void*)&hs_b };
        hipLaunchCooperativeKernel((const void*)lstm_coop, dim3(256), dim3(256),
                                   args, 0, stream);
    }

    logits_kernel<<<NT, 64, 0, stream>>>(hs_f, hs_b, Wd, bd, out + OUT_LOGITS);
    lens_kernel<<<BB, 256, 0, stream>>>(text, out + OUT_LENS, leni);
    crf_kernel<<<BB, 128, 0, stream>>>(out + OUT_LOGITS, labels, trans, leni,
                                       bp, out + OUT_LL, out + OUT_TAGS);
}

// Round 5
// 1577.774 us; speedup vs baseline: 1.6683x; 1.6683x over previous
//
#include <hip/hip_runtime.h>
#include <hip/hip_bf16.h>
#include <math.h>

// Problem constants
#define BB 64
#define TT 256
#define EE 300
#define DD 600
#define KP 608        // K padded to 19*32 for MFMA
#define HH 512
#define G4 2048
#define LL 9
#define NT (BB*TT)

typedef __attribute__((ext_vector_type(8))) short short8;   // 8 bf16
typedef __attribute__((ext_vector_type(4))) float floatx4;  // MFMA acc

// ---------------- Workspace layout (bytes) ----------------
#define XZF_OFF  ((size_t)0)
#define XZ_BYTES ((size_t)NT * G4 * 2)                  // 67108864
#define XZB_OFF  (XZF_OFF + XZ_BYTES)
#define HSR_OFF  (XZB_OFF + XZ_BYTES)                   // hs region, 33554432
#define HS_BYTES ((size_t)NT * HH * 2)                  // 16777216
#define HSF_OFF  (HSR_OFF)
#define HSB_OFF  (HSR_OFF + HS_BYTES)
// aliases inside hs region (dead before their overwriters run):
#define XG_OFF   (HSR_OFF)                              // 16384*608*2 (dead before lstm)
#define WKT_OFF  (HSR_OFF + 19922944)                   // 2*2048*608*2 (dead before lstm)
#define BP_OFF   (HSR_OFF + 25165824)                   // written after logits reads hs
#define WRT_OFF  (HSR_OFF + (size_t)2 * HS_BYTES)       // 2*2048*512*2 = 4194304
#define HB_OFF   (WRT_OFF + 4194304)                    // tagged u32: 2dir*2slot*64*512*4
#define HB_BYTES ((size_t)2 * 2 * BB * HH * 4)          // 524288
#define LEN_OFF  (HB_OFF + HB_BYTES)

// Output layout (floats)
#define OUT_LOGITS 0
#define OUT_LENS   (BB*TT*LL)
#define OUT_LL     (OUT_LENS + BB)
#define OUT_TAGS   (OUT_LL + BB)

// ---------------------------------------------------------------------------
// Prep 1: gather embeddings -> xg[n][608] bf16 (zero-padded K)
// ---------------------------------------------------------------------------
__global__ __launch_bounds__(256) void prep_xg(
    const int* __restrict__ text, const int* __restrict__ sent,
    const float* __restrict__ wemb, const float* __restrict__ semb,
    __hip_bfloat16* __restrict__ xg)
{
    int n = blockIdx.x;
    int ti = text[n], si = sent[n];
    __hip_bfloat16* o = xg + (size_t)n * KP;
    for (int k = threadIdx.x; k < KP; k += 256) {
        float v = 0.f;
        if (k < EE)      v = wemb[(size_t)ti * EE + k];
        else if (k < DD) v = semb[(size_t)si * EE + (k - EE)];
        o[k] = __float2bfloat16(v);
    }
}

// ---------------------------------------------------------------------------
// Prep 2: LDS-tiled transpose + bf16 convert.
// in: W[dir] = [Din][2048] f32 ; out: out[dir] = [2048][Dpad] bf16
// grid (2048/64, ceil(Dpad/64), 2), block 256
// ---------------------------------------------------------------------------
__global__ __launch_bounds__(256) void transpose_w(
    const float* __restrict__ Wf, const float* __restrict__ Wb,
    __hip_bfloat16* __restrict__ outT, int Din, int Dpad)
{
    int dir = blockIdx.z;
    const float* W = dir ? Wb : Wf;
    __hip_bfloat16* o = outT + (size_t)dir * G4 * Dpad;
    int n0 = blockIdx.x * 64, d0 = blockIdx.y * 64;
    __shared__ float tile[64][65];
    int c = threadIdx.x & 63, r4 = threadIdx.x >> 6;
    #pragma unroll
    for (int rr = 0; rr < 64; rr += 4) {
        int d = d0 + rr + r4;
        tile[rr + r4][c] = (d < Din) ? W[(size_t)d * G4 + n0 + c] : 0.f;
    }
    __syncthreads();
    #pragma unroll
    for (int rr = 0; rr < 64; rr += 4) {
        int n = n0 + rr + r4;
        int d = d0 + c;
        if (d < Dpad) o[(size_t)n * Dpad + d] = __float2bfloat16(tile[c][rr + r4]);
    }
}

// ---------------------------------------------------------------------------
// Embed GEMM: xz[dir][n][col] = xg @ Wk + b   (bf16 MFMA, frags from L2)
// ---------------------------------------------------------------------------
__global__ __launch_bounds__(256) void embed_gemm(
    const __hip_bfloat16* __restrict__ xg,
    const __hip_bfloat16* __restrict__ WkT,
    const float* __restrict__ b_f, const float* __restrict__ b_b,
    __hip_bfloat16* __restrict__ xz_f, __hip_bfloat16* __restrict__ xz_b)
{
    int dir = blockIdx.z;
    const __hip_bfloat16* wt = WkT + (size_t)dir * G4 * KP;
    const float* bias = dir ? b_b : b_f;
    __hip_bfloat16* xz = dir ? xz_b : xz_f;

    int n0 = blockIdx.x * 64;
    int c0 = blockIdx.y * 64;
    int wave = threadIdx.x >> 6, lane = threadIdx.x & 63;
    int mt2 = (wave & 1) * 2;
    int nt2 = (wave >> 1) * 2;
    int lm = lane & 15, lk8 = (lane >> 4) * 8;

    const short8* ap[2], *bp[2];
    ap[0] = (const short8*)(xg + (size_t)(n0 + (mt2+0)*16 + lm) * KP + lk8);
    ap[1] = (const short8*)(xg + (size_t)(n0 + (mt2+1)*16 + lm) * KP + lk8);
    bp[0] = (const short8*)(wt + (size_t)(c0 + (nt2+0)*16 + lm) * KP + lk8);
    bp[1] = (const short8*)(wt + (size_t)(c0 + (nt2+1)*16 + lm) * KP + lk8);

    floatx4 acc[2][2] = {};
    for (int kc = 0; kc < KP/32; ++kc) {
        short8 a0 = ap[0][kc*4];
        short8 a1 = ap[1][kc*4];
        short8 b0 = bp[0][kc*4];
        short8 b1 = bp[1][kc*4];
        acc[0][0] = __builtin_amdgcn_mfma_f32_16x16x32_bf16(a0, b0, acc[0][0], 0,0,0);
        acc[0][1] = __builtin_amdgcn_mfma_f32_16x16x32_bf16(a0, b1, acc[0][1], 0,0,0);
        acc[1][0] = __builtin_amdgcn_mfma_f32_16x16x32_bf16(a1, b0, acc[1][0], 0,0,0);
        acc[1][1] = __builtin_amdgcn_mfma_f32_16x16x32_bf16(a1, b1, acc[1][1], 0,0,0);
    }

    float bias0 = bias[c0 + (nt2+0)*16 + lm];
    float bias1 = bias[c0 + (nt2+1)*16 + lm];
    int lr = (lane >> 4) * 4;
    #pragma unroll
    for (int mi = 0; mi < 2; ++mi)
        #pragma unroll
        for (int ni = 0; ni < 2; ++ni) {
            int col = c0 + (nt2+ni)*16 + lm;
            float bs = ni ? bias1 : bias0;
            #pragma unroll
            for (int r = 0; r < 4; ++r) {
                int row = n0 + (mt2+mi)*16 + lr + r;
                xz[(size_t)row * G4 + col] = __float2bfloat16(acc[mi][ni][r] + bs);
            }
        }
}

// ---------------------------------------------------------------------------
// Persistent LSTM. 256 blocks (1/CU) x 256 threads, cooperative.
// block = (dir, rowgroup16, hgroup16), wave = gate. Wr slice in regs.
// Shared tagged ping-pong h exchange: each u32 = ((t)<<16 | bf16), written
// once per producer, read by the 32 group peers. Tag travels atomically with
// the value -> detection and load are the same L3 round trip. Consumer does
// 16 coalesced u64 agent loads; re-poll = branchless reload-all + s_sleep
// (fixes R4's 32-scalar-load / divergent-repoll codegen).
// WAR-safe over period-2 slots by the publish-implies-consumed induction.
// ---------------------------------------------------------------------------
__global__ __launch_bounds__(256, 1) void lstm_coop(
    const __hip_bfloat16* __restrict__ xz_f, const __hip_bfloat16* __restrict__ xz_b,
    const __hip_bfloat16* __restrict__ WrT,   // [2][2048][512]
    unsigned* __restrict__ hbx,               // [2dir][2slot][64][512] tagged u32
    __hip_bfloat16* __restrict__ hs_f, __hip_bfloat16* __restrict__ hs_b)
{
    int blk = blockIdx.x;
    int dir = blk >> 7, sub = blk & 127;
    int r0 = (sub >> 5) * 16;     // 4 rowgroups
    int h0 = (sub & 31) * 16;     // 32 hgroups
    int tid = threadIdx.x;
    int gate = tid >> 6, lane = tid & 63;
    int lm = lane & 15, lk8 = (lane >> 4) * 8;

    const __hip_bfloat16* xz = dir ? xz_b : xz_f;
    __hip_bfloat16* hs = dir ? hs_b : hs_f;
    const __hip_bfloat16* wrt = WrT + (size_t)dir * G4 * HH;
    unsigned* hbd = hbx + (size_t)dir * 2 * BB * HH;

    // persistent weight fragments (gate's 16 cols x full K=512)
    short8 bfrag[16];
    {
        const short8* wp = (const short8*)(wrt + (size_t)(gate*HH + h0 + lm) * HH + lk8);
        #pragma unroll
        for (int kc = 0; kc < 16; ++kc) bfrag[kc] = wp[kc*4];
    }

    __shared__ unsigned short htile[16][520];   // h(t) rows r0..r0+15, padded
    __shared__ float zbuf[4][16][17];

    // epilogue mapping: threads 0..127 each own (row er, cols ec, ec+1)
    int er = tid >> 3, ec = (tid & 7) * 2;
    float c0st = 0.f, c1st = 0.f;

    // xz source rows for z-phase (wave handles rows zr..zr+3)
    int zr = (lane >> 4) * 4;

    for (int t = 0; t < TT; ++t) {
        int tok = dir ? (TT - 1 - t) : t;

        // prefetch xz operand (independent of h) — in flight during poll
        float xzv[4];
        #pragma unroll
        for (int r = 0; r < 4; ++r) {
            int n = (r0 + zr + r) * TT + tok;
            xzv[r] = __bfloat162float(xz[(size_t)n * G4 + gate*HH + h0 + lm]);
        }

        // poll tagged h(t) row-tile: 16 coalesced u64 loads, branchless verify
        unsigned long long v[16];
        {
            const unsigned long long* src = (const unsigned long long*)
                (hbd + (size_t)(t & 1) * BB * HH + (size_t)r0 * HH);
            const unsigned long long pat =
                ((unsigned long long)(unsigned)t << 48) |
                ((unsigned long long)(unsigned)t << 16);
            for (;;) {
                #pragma unroll
                for (int q = 0; q < 16; ++q)
                    v[q] = __hip_atomic_load(src + tid + 256*q,
                            __ATOMIC_RELAXED, __HIP_MEMORY_SCOPE_AGENT);
                unsigned long long bad = 0;
                #pragma unroll
                for (int q = 0; q < 16; ++q)
                    bad |= (v[q] ^ pat) & 0xFFFF0000FFFF0000ULL;
                if (bad == 0) break;
                __builtin_amdgcn_s_sleep(2);
            }
        }
        // stage into LDS (strip tags): u64 q at idx=tid+256q -> row idx>>8,
        // colpair idx&255
        #pragma unroll
        for (int q = 0; q < 16; ++q) {
            int idx = tid + 256*q;
            int row = idx >> 8, cp = idx & 255;
            unsigned lo = (unsigned)(v[q] & 0xffffu);
            unsigned hi = (unsigned)((v[q] >> 32) & 0xffffu);
            *(unsigned*)&htile[row][cp * 2] = lo | (hi << 16);
        }
        __syncthreads();

        floatx4 acc = {};
        #pragma unroll
        for (int kc = 0; kc < 16; ++kc) {
            short8 a = *(const short8*)&htile[lm][kc * 32 + lk8];
            acc = __builtin_amdgcn_mfma_f32_16x16x32_bf16(a, bfrag[kc], acc, 0,0,0);
        }

        // publish z-tile to LDS for gate exchange
        #pragma unroll
        for (int r = 0; r < 4; ++r)
            zbuf[gate][zr + r][lm] = acc[r] + xzv[r];
        __syncthreads();

        if (tid < 128) {
            float zi0 = zbuf[0][er][ec],   zi1 = zbuf[0][er][ec+1];
            float zf0 = zbuf[1][er][ec],   zf1 = zbuf[1][er][ec+1];
            float zg0 = zbuf[2][er][ec],   zg1 = zbuf[2][er][ec+1];
            float zo0 = zbuf[3][er][ec],   zo1 = zbuf[3][er][ec+1];
            float si0 = 1.f/(1.f+__expf(-zi0)), si1 = 1.f/(1.f+__expf(-zi1));
            float sf0 = 1.f/(1.f+__expf(-zf0)), sf1 = 1.f/(1.f+__expf(-zf1));
            float so0 = 1.f/(1.f+__expf(-zo0)), so1 = 1.f/(1.f+__expf(-zo1));
            c0st = sf0 * c0st + si0 * tanhf(zg0);
            c1st = sf1 * c1st + si1 * tanhf(zg1);
            float h0v = so0 * tanhf(c0st);
            float h1v = so1 * tanhf(c1st);
            unsigned u0 = (unsigned)__builtin_bit_cast(unsigned short, __float2bfloat16(h0v));
            unsigned u1 = (unsigned)__builtin_bit_cast(unsigned short, __float2bfloat16(h1v));
            unsigned tg = (unsigned)(t + 1) << 16;
            unsigned long long pay =
                ((unsigned long long)(tg | u1) << 32) | (unsigned long long)(tg | u0);
            __hip_atomic_store(
                (unsigned long long*)(hbd + (size_t)((t+1) & 1) * BB * HH
                                          + (size_t)(r0 + er) * HH + h0 + ec),
                pay, __ATOMIC_RELAXED, __HIP_MEMORY_SCOPE_AGENT);
            // plain row-major copy for downstream logits kernel
            *(unsigned*)(hs + ((size_t)(r0 + er) * TT + tok) * HH + h0 + ec) =
                u0 | (u1 << 16);
        }
        // no extra barrier: next iteration's post-stage __syncthreads
        // separates epilogue zbuf reads from the next zbuf writes.
    }
}

// ---------------------------------------------------------------------------
// logits = [hf, hb] @ Wd + bd
// ---------------------------------------------------------------------------
__global__ __launch_bounds__(64) void logits_kernel(
    const __hip_bfloat16* __restrict__ hs_f, const __hip_bfloat16* __restrict__ hs_b,
    const float* __restrict__ Wd, const float* __restrict__ bd,
    float* __restrict__ out)
{
    int n = blockIdx.x;
    int tid = threadIdx.x;
    __shared__ float red[64][10];
    float acc[LL] = {};
    for (int kk = 0; kk < 16; ++kk) {
        int k = kk * 64 + tid;
        float hv = (k < HH) ? __bfloat162float(hs_f[(size_t)n * HH + k])
                            : __bfloat162float(hs_b[(size_t)n * HH + (k - HH)]);
        const float* w = Wd + (size_t)k * LL;
        #pragma unroll
        for (int l = 0; l < LL; ++l) acc[l] += hv * w[l];
    }
    #pragma unroll
    for (int l = 0; l < LL; ++l) red[tid][l] = acc[l];
    __syncthreads();
    for (int s = 32; s > 0; s >>= 1) {
        if (tid < s)
            for (int l = 0; l < LL; ++l) red[tid][l] += red[tid + s][l];
        __syncthreads();
    }
    if (tid < LL) out[(size_t)n * LL + tid] = red[0][tid] + bd[tid];
}

// ---------------------------------------------------------------------------
// text lengths
// ---------------------------------------------------------------------------
__global__ __launch_bounds__(256) void lens_kernel(
    const int* __restrict__ text, float* __restrict__ out_lens, int* __restrict__ len_i)
{
    int b = blockIdx.x, tid = threadIdx.x;
    __shared__ int sred[256];
    sred[tid] = (text[b * TT + tid] != 0) ? 1 : 0;
    __syncthreads();
    for (int s = 128; s > 0; s >>= 1) {
        if (tid < s) sred[tid] += sred[tid + s];
        __syncthreads();
    }
    if (tid == 0) { out_lens[b] = (float)sred[0]; len_i[b] = sred[0]; }
}

// ---------------------------------------------------------------------------
// CRF log-likelihood + Viterbi decode (one block per batch item)
// ---------------------------------------------------------------------------
__global__ __launch_bounds__(128) void crf_kernel(
    const float* __restrict__ logits, const int* __restrict__ labels,
    const float* __restrict__ trans, const int* __restrict__ len_i,
    int* __restrict__ bp, float* __restrict__ out_ll, float* __restrict__ out_tags)
{
    int b = blockIdx.x, tid = threadIdx.x;
    int len = len_i[b];
    const float* lg = logits + (size_t)b * TT * LL;
    const int* lab = labels + b * TT;

    __shared__ float tr[81];
    __shared__ float alpha[LL], vit[LL], newa[LL], newv[LL];
    __shared__ int newbp[LL];
    __shared__ float partial[128];

    if (tid < 81) tr[tid] = trans[tid];
    if (tid < LL) { alpha[tid] = lg[tid]; vit[tid] = lg[tid]; }
    __syncthreads();

    float up = 0.f;
    for (int t = tid; t < TT; t += 128) {
        float m = (t < len) ? 1.f : 0.f;
        up += m * lg[t * LL + lab[t]];
        if (t >= 1) up += m * tr[lab[t - 1] * LL + lab[t]];
    }
    partial[tid] = up;
    __syncthreads();
    for (int s = 64; s > 0; s >>= 1) {
        if (tid < s) partial[tid] += partial[tid + s];
        __syncthreads();
    }

    for (int t = 1; t < TT; ++t) {
        bool m = t < len;
        if (tid < LL) {
            int j = tid;
            float mx = -1e30f;
            #pragma unroll
            for (int i = 0; i < LL; ++i) mx = fmaxf(mx, alpha[i] + tr[i * LL + j]);
            float s = 0.f;
            #pragma unroll
            for (int i = 0; i < LL; ++i) s += __expf(alpha[i] + tr[i * LL + j] - mx);
            newa[j] = mx + __logf(s) + lg[t * LL + j];
        } else if (tid >= 64 && tid < 64 + LL) {
            int j = tid - 64;
            float best = -1e30f; int bi = 0;
            #pragma unroll
            for (int i = 0; i < LL; ++i) {
                float sc = vit[i] + tr[i * LL + j];
                if (sc > best) { best = sc; bi = i; }
            }
            newv[j] = best + lg[t * LL + j];
            newbp[j] = bi;
        }
        __syncthreads();
        if (tid < LL) {
            if (m) alpha[tid] = newa[tid];
        } else if (tid >= 64 && tid < 64 + LL) {
            int j = tid - 64;
            if (m) vit[j] = newv[j];
            bp[((size_t)b * (TT - 1) + (t - 1)) * LL + j] = m ? newbp[j] : j;
        }
        __syncthreads();
    }

    if (tid == 0) {
        float mx = -1e30f;
        #pragma unroll
        for (int j = 0; j < LL; ++j) mx = fmaxf(mx, alpha[j]);
        float s = 0.f;
        #pragma unroll
        for (int j = 0; j < LL; ++j) s += __expf(alpha[j] - mx);
        out_ll[b] = partial[0] - (mx + __logf(s));

        float bv = vit[0]; int last = 0;
        #pragma unroll
        for (int j = 1; j < LL; ++j) if (vit[j] > bv) { bv = vit[j]; last = j; }
        out_tags[b * TT + (TT - 1)] = (float)last;
        int tag = last;
        for (int s2 = TT - 2; s2 >= 0; --s2) {
            tag = bp[((size_t)b * (TT - 1) + s2) * LL + tag];
            out_tags[b * TT + s2] = (float)tag;
        }
    }
}

// ---------------------------------------------------------------------------
extern "C" void kernel_launch(void* const* d_in, const int* in_sizes, int n_in,
                              void* d_out, int out_size, void* d_ws, size_t ws_size,
                              hipStream_t stream)
{
    const int*   text  = (const int*)d_in[0];
    const int*   sent  = (const int*)d_in[1];
    const int*   labels= (const int*)d_in[2];
    const float* wemb  = (const float*)d_in[3];
    const float* semb  = (const float*)d_in[4];
    const float* Wk_f  = (const float*)d_in[5];
    const float* Wr_f  = (const float*)d_in[6];
    const float* b_f   = (const float*)d_in[7];
    const float* Wk_b  = (const float*)d_in[8];
    const float* Wr_b  = (const float*)d_in[9];
    const float* b_b   = (const float*)d_in[10];
    const float* Wd    = (const float*)d_in[11];
    const float* bd    = (const float*)d_in[12];
    const float* trans = (const float*)d_in[13];
    float* out = (float*)d_out;

    char* ws = (char*)d_ws;
    __hip_bfloat16* xz_f = (__hip_bfloat16*)(ws + XZF_OFF);
    __hip_bfloat16* xz_b = (__hip_bfloat16*)(ws + XZB_OFF);
    __hip_bfloat16* hs_f = (__hip_bfloat16*)(ws + HSF_OFF);
    __hip_bfloat16* hs_b = (__hip_bfloat16*)(ws + HSB_OFF);
    __hip_bfloat16* xg   = (__hip_bfloat16*)(ws + XG_OFF);
    __hip_bfloat16* WkT  = (__hip_bfloat16*)(ws + WKT_OFF);
    __hip_bfloat16* WrT  = (__hip_bfloat16*)(ws + WRT_OFF);
    unsigned*       hbx  = (unsigned*)(ws + HB_OFF);
    int*      bp    = (int*)(ws + BP_OFF);
    int*      leni  = (int*)(ws + LEN_OFF);

    prep_xg <<<NT,  256, 0, stream>>>(text, sent, wemb, semb, xg);
    // LDS-tiled transposes (coalesced both sides)
    transpose_w<<<dim3(G4/64, (KP+63)/64, 2), 256, 0, stream>>>(Wk_f, Wk_b, WkT, DD, KP);
    transpose_w<<<dim3(G4/64, HH/64, 2),      256, 0, stream>>>(Wr_f, Wr_b, WrT, HH, HH);
    // zero tagged h exchange (tag 0 == h(0) = 0) + len scratch
    hipMemsetAsync(ws + HB_OFF, 0, HB_BYTES + 256, stream);

    embed_gemm<<<dim3(NT/64, G4/64, 2), 256, 0, stream>>>(
        xg, WkT, b_f, b_b, xz_f, xz_b);

    {
        void* args[] = { (void*)&xz_f, (void*)&xz_b, (void*)&WrT,
                         (void*)&hbx, (void*)&hs_f, (void*)&hs_b };
        hipLaunchCooperativeKernel((const void*)lstm_coop, dim3(256), dim3(256),
                                   args, 0, stream);
    }

    logits_kernel<<<NT, 64, 0, stream>>>(hs_f, hs_b, Wd, bd, out + OUT_LOGITS);
    lens_kernel<<<BB, 256, 0, stream>>>(text, out + OUT_LENS, leni);
    crf_kernel<<<BB, 128, 0, stream>>>(out + OUT_LOGITS, labels, trans, leni,
                                       bp, out + OUT_LL, out + OUT_TAGS);
}